// Round 1
// baseline (318.392 us; speedup 1.0000x reference)
//
#include <hip/hip_runtime.h>

typedef unsigned short u16;
typedef unsigned int u32;
typedef _Float16 half8 __attribute__((ext_vector_type(8)));
typedef __fp16 fp16x2 __attribute__((ext_vector_type(2)));
typedef float f32x16 __attribute__((ext_vector_type(16)));

union HU { uint4 u; half8 h; };
union PK { fp16x2 h; u32 u; };

__device__ __forceinline__ u16 f2h(float f) {
  union { _Float16 h; u16 u; } c;
  c.h = (_Float16)f;
  return c.u;
}

// Pack weights (O=64, I=64, 3, 3) fp32 -> fp16 in exact A-fragment order:
// wbuf[((t*2 + mt)*64 + lane)*8 + j] = w[m][c][rs]
//   m = mt*32 + (lane&31), k = t*16 + (lane>>5)*8 + j, rs = k>>6, c = k&63
// K ordering: k = rs*64 + c  (rs-major, c-minor); rs = kh*3+kw
__global__ void prep_w(const float* __restrict__ w, u16* __restrict__ wbuf) {
  int idx = blockIdx.x * 256 + threadIdx.x;  // 36864 total
  int j    = idx & 7;
  int lane = (idx >> 3) & 63;
  int mt   = (idx >> 9) & 1;
  int t    = idx >> 10;
  int m  = mt * 32 + (lane & 31);
  int k  = t * 16 + (lane >> 5) * 8 + j;
  int rs = k >> 6;
  int c  = k & 63;
  wbuf[idx] = f2h(w[(m * 64 + c) * 9 + rs]);
}

// Implicit-GEMM conv: M = O = 64 (2 mtiles), N = pixels, K = 576.
// Split-K schedule: K processed in two 32-channel halves (kh = 0,1) so the
// x-tile LDS is 32 KB -> 4 blocks/CU (32 waves/CU) instead of 2 (16 waves).
// Block: one n (batch), 2 output rows, 128 w, all 64 o. 512 threads = 8 waves.
// Wave = (rw = wave>>2, mt = (wave>>1)&1, np = wave&1):
//   one output row, ONE mtile, TWO 32-pixel ntiles (pixels np*64+{0,32}+l31).
//   Each A-fragment global load feeds 2 MFMAs -> halves wbuf L2 traffic.
// LDS: [row 4][cblk 4][w 128][c 8] fp16 (32 KB) — conflict-free:
//   staging writes lane->w stride-16B b128, K-loop B reads lane->pixel stride-16B b128.
__global__ __launch_bounds__(512, 8) void conv_mfma(
    const float* __restrict__ x, const u16* __restrict__ wbuf,
    const float* __restrict__ bias, float* __restrict__ out) {
  __shared__ u16 xlds[4 * 4 * 128 * 8];  // 32 KB

  int tid = threadIdx.x;
  int lane = tid & 63;
  int wave = tid >> 6;  // 0..7
  int bid = blockIdx.x;
  int nb = bid & 31;   // batch
  int hg = bid >> 5;   // row-group [0,64)
  int h0 = hg * 2;

  int l31 = lane & 31;
  int half = lane >> 5;
  int rw = wave >> 2;        // output row within block
  int mt = (wave >> 1) & 1;  // this wave's mtile
  int np = wave & 1;         // pixel-pair group: ntiles np*2, np*2+1

  f32x16 acc[2] = {};  // [ntile within pair]

#pragma unroll
  for (int kh = 0; kh < 2; ++kh) {
    if (kh) __syncthreads();  // K-loop of previous half must drain before overwrite

    // ---- stage x (channels kh*32 .. kh*32+31) -> LDS, coalesced (lane->w),
    //      register transpose 8c via pkrtz ----
    // slab = (row[4], cblk[4]) = 16 slabs; wave handles 2; lane covers w and w+64.
#pragma unroll
    for (int s = 0; s < 2; ++s) {
      int id = wave * 2 + s;   // 0..15
      int row = id >> 2;       // 0..3
      int cblk = id & 3;
      int hin = h0 - 1 + row;
      int c0 = kh * 32 + cblk * 8;
      bool inb = (hin >= 0 && hin < 128);
      const float* base = x + (((size_t)(nb * 64 + c0) * 128 + hin) * 128);
#pragma unroll
      for (int w2 = 0; w2 < 2; ++w2) {
        int w = w2 * 64 + lane;
        uint4 v = make_uint4(0u, 0u, 0u, 0u);
        if (inb) {
          float f[8];
#pragma unroll
          for (int j = 0; j < 8; ++j) f[j] = base[(size_t)j * 16384 + w];
          PK p0, p1, p2, p3;
          p0.h = __builtin_amdgcn_cvt_pkrtz(f[0], f[1]);
          p1.h = __builtin_amdgcn_cvt_pkrtz(f[2], f[3]);
          p2.h = __builtin_amdgcn_cvt_pkrtz(f[4], f[5]);
          p3.h = __builtin_amdgcn_cvt_pkrtz(f[6], f[7]);
          v = make_uint4(p0.u, p1.u, p2.u, p3.u);
        }
        *(uint4*)&xlds[((row * 4 + cblk) * 128 + w) * 8] = v;
      }
    }
    __syncthreads();

    // ---- K-loop over this half's 18 ktiles ----
#pragma unroll
    for (int r = 0; r < 3; ++r) {
      int row = rw + r;  // LDS row index (input row h0-1+row)
#pragma unroll
      for (int s = 0; s < 3; ++s) {
        int pin0 = np * 64 + l31 + s - 1;
        int pin1 = pin0 + 32;
        bool ob0 = (unsigned)pin0 >= 128u;  // only np=0, s=0, l31=0
        bool ob1 = (unsigned)pin1 >= 128u;  // only np=1, s=2, l31=31
        int pc0 = ob0 ? 0 : pin0;
        int pc1 = ob1 ? 0 : pin1;
#pragma unroll
        for (int tc = 0; tc < 2; ++tc) {
          int t = (r * 3 + s) * 4 + kh * 2 + tc;  // global ktile id
          int cblk = tc * 2 + half;               // local cblk in this half
          HU a, b0, b1;
          a.u = *(const uint4*)&wbuf[(t * 2 + mt) * 512 + lane * 8];
          b0.u = *(const uint4*)&xlds[((row * 4 + cblk) * 128 + pc0) * 8];
          b1.u = *(const uint4*)&xlds[((row * 4 + cblk) * 128 + pc1) * 8];
          if (ob0) b0.u = make_uint4(0u, 0u, 0u, 0u);
          if (ob1) b1.u = make_uint4(0u, 0u, 0u, 0u);
          acc[0] = __builtin_amdgcn_mfma_f32_32x32x16_f16(a.h, b0.h, acc[0], 0, 0, 0);
          acc[1] = __builtin_amdgcn_mfma_f32_32x32x16_f16(a.h, b1.h, acc[1], 0, 0, 0);
        }
      }
    }
  }

  // ---- epilogue: C/D layout col = lane&31 (pixel), row = (reg&3)+8*(reg>>2)+4*half (o) ----
  int h = h0 + rw;
#pragma unroll
  for (int n = 0; n < 2; ++n) {
    int p = np * 64 + n * 32 + l31;
    size_t outbase = (size_t)nb * 64 * 16384 + (size_t)h * 128 + p;
#pragma unroll
    for (int reg = 0; reg < 16; ++reg) {
      int o = mt * 32 + (reg & 3) + 8 * (reg >> 2) + 4 * half;
      out[outbase + (size_t)o * 16384] = acc[n][reg] + bias[o];
    }
  }
}

extern "C" void kernel_launch(void* const* d_in, const int* in_sizes, int n_in,
                              void* d_out, int out_size, void* d_ws, size_t ws_size,
                              hipStream_t stream) {
  const float* x = (const float*)d_in[0];
  const float* w = (const float*)d_in[1];
  const float* b = (const float*)d_in[2];
  float* out = (float*)d_out;
  u16* wbuf = (u16*)d_ws;  // 36864 fp16 = 73728 B of scratch

  prep_w<<<dim3(144), dim3(256), 0, stream>>>(w, wbuf);
  conv_mfma<<<dim3(2048), dim3(512), 0, stream>>>(x, wbuf, b, out);
}

// Round 2
// 298.303 us; speedup vs baseline: 1.0673x; 1.0673x over previous
//
#include <hip/hip_runtime.h>

typedef unsigned short u16;
typedef unsigned int u32;
typedef _Float16 half8 __attribute__((ext_vector_type(8)));
typedef __fp16 fp16x2 __attribute__((ext_vector_type(2)));
typedef float f32x16 __attribute__((ext_vector_type(16)));

union HU { uint4 u; half8 h; };
union PK { fp16x2 h; u32 u; };

__device__ __forceinline__ u16 f2h(float f) {
  union { _Float16 h; u16 u; } c;
  c.h = (_Float16)f;
  return c.u;
}

// Pack weights (O=64, I=64, 3, 3) fp32 -> fp16 in exact A-fragment order:
// wbuf[((t*2 + mt)*64 + lane)*8 + j] = w[m][c][rs]
//   m = mt*32 + (lane&31), k = t*16 + (lane>>5)*8 + j, rs = k>>6, c = k&63
// K ordering: k = rs*64 + c  (rs-major, c-minor); rs = kh*3+kw
__global__ void prep_w(const float* __restrict__ w, u16* __restrict__ wbuf) {
  int idx = blockIdx.x * 256 + threadIdx.x;  // 36864 total
  int j    = idx & 7;
  int lane = (idx >> 3) & 63;
  int mt   = (idx >> 9) & 1;
  int t    = idx >> 10;
  int m  = mt * 32 + (lane & 31);
  int k  = t * 16 + (lane >> 5) * 8 + j;
  int rs = k >> 6;
  int c  = k & 63;
  wbuf[idx] = f2h(w[(m * 64 + c) * 9 + rs]);
}

// Implicit-GEMM conv: M = O = 64 (2 mtiles), N = pixels, K = 576.
// v2 schedule: block = ONE output row x 128 px x all 64 o. 512 thr = 8 waves.
// Wave = (mt = wave>>2, nq = wave&3): ONE 32x32 output tile -> acc is a single
// f32x16 (16 regs), so the wave fits well under a 73-reg unified budget
// (launch_bounds(512,7)); round-1's (512,8)=64-reg budget spilled 32-reg acc
// to scratch (+270 MB HBM traffic). Split-K in two 32-channel halves keeps
// the x-tile LDS small (3 rows x 4 cblk x 130 px-slots x 8 ch ~ 24.4 KB) so
// LDS never caps occupancy; registers decide (3-4 blocks/CU, 75-100%).
// Halo-padded pixel axis: slot p+1, slots 0 and 129 pre-zeroed once ->
// K-loop has ZERO boundary logic (no cndmask, no clamps).
// LDS conflict-free: staging writes and K-loop B reads are both contiguous
// 16 B per lane (b128).
__global__ __launch_bounds__(512, 7) void conv_mfma(
    const float* __restrict__ x, const u16* __restrict__ wbuf,
    const float* __restrict__ bias, float* __restrict__ out) {
  // [slab 12 = row3 x cblk4][px-slot 130][ch 8] fp16, ~24.4 KB
  __shared__ u16 xlds[12 * 130 * 8];

  int tid = threadIdx.x;
  int lane = tid & 63;
  int wave = tid >> 6;  // 0..7
  int bid = blockIdx.x;
  int nb = bid & 31;   // batch
  int h  = bid >> 5;   // output row [0,128)

  int l31 = lane & 63 & 31;
  int half = lane >> 5;
  int mt = wave >> 2;  // this wave's mtile
  int nq = wave & 3;   // this wave's 32-pixel ntile

  // zero the halo slots (slot 0 and 129 of each slab) once; staging only
  // ever writes slots 1..128, so these stay zero across both kh phases.
  if (tid < 12) {
    *(uint4*)&xlds[((tid * 130) + 0) * 8]   = make_uint4(0u, 0u, 0u, 0u);
    *(uint4*)&xlds[((tid * 130) + 129) * 8] = make_uint4(0u, 0u, 0u, 0u);
  }

  f32x16 acc = {};

#pragma unroll
  for (int kh = 0; kh < 2; ++kh) {
    if (kh) __syncthreads();  // previous half's K-loop must drain before overwrite

    // ---- stage x (channels kh*32 .. +31) -> LDS ----
    // 24 tasks = (row 3, cblk 4, w-half 2); each wave does 3.
#pragma unroll
    for (int s = 0; s < 3; ++s) {
      int id = wave * 3 + s;   // 0..23
      int row = id >> 3;       // 0..2
      int cblk = (id >> 1) & 3;
      int w2 = id & 1;
      int hin = h - 1 + row;
      int c0 = kh * 32 + cblk * 8;
      bool inb = (hin >= 0 && hin < 128);
      const float* base = x + (((size_t)(nb * 64 + c0) * 128 + hin) * 128);
      int w = w2 * 64 + lane;
      uint4 v = make_uint4(0u, 0u, 0u, 0u);
      if (inb) {
        float f[8];
#pragma unroll
        for (int j = 0; j < 8; ++j) f[j] = base[(size_t)j * 16384 + w];
        PK p0, p1, p2, p3;
        p0.h = __builtin_amdgcn_cvt_pkrtz(f[0], f[1]);
        p1.h = __builtin_amdgcn_cvt_pkrtz(f[2], f[3]);
        p2.h = __builtin_amdgcn_cvt_pkrtz(f[4], f[5]);
        p3.h = __builtin_amdgcn_cvt_pkrtz(f[6], f[7]);
        v = make_uint4(p0.u, p1.u, p2.u, p3.u);
      }
      *(uint4*)&xlds[(((row * 4 + cblk) * 130) + 1 + w) * 8] = v;
    }
    __syncthreads();

    // ---- K-loop over this half's 18 ktiles ----
#pragma unroll
    for (int r = 0; r < 3; ++r) {
#pragma unroll
      for (int s = 0; s < 3; ++s) {
        int ps = nq * 32 + l31 + s;  // halo-indexed pixel slot, 0..129, no clamp
#pragma unroll
        for (int tc = 0; tc < 2; ++tc) {
          int t = (r * 3 + s) * 4 + kh * 2 + tc;  // global ktile id
          int cblk = tc * 2 + half;               // local cblk in this half
          HU a, b;
          a.u = *(const uint4*)&wbuf[(t * 2 + mt) * 512 + lane * 8];
          b.u = *(const uint4*)&xlds[(((r * 4 + cblk) * 130) + ps) * 8];
          acc = __builtin_amdgcn_mfma_f32_32x32x16_f16(a.h, b.h, acc, 0, 0, 0);
        }
      }
    }
  }

  // ---- epilogue: C/D layout col = lane&31 (pixel), row = (reg&3)+8*(reg>>2)+4*half (o) ----
  int p = nq * 32 + l31;
  size_t outbase = (size_t)nb * 64 * 16384 + (size_t)h * 128 + p;
#pragma unroll
  for (int reg = 0; reg < 16; ++reg) {
    int o = mt * 32 + (reg & 3) + 8 * (reg >> 2) + 4 * half;
    out[outbase + (size_t)o * 16384] = acc[reg] + bias[o];
  }
}

extern "C" void kernel_launch(void* const* d_in, const int* in_sizes, int n_in,
                              void* d_out, int out_size, void* d_ws, size_t ws_size,
                              hipStream_t stream) {
  const float* x = (const float*)d_in[0];
  const float* w = (const float*)d_in[1];
  const float* b = (const float*)d_in[2];
  float* out = (float*)d_out;
  u16* wbuf = (u16*)d_ws;  // 36864 fp16 = 73728 B of scratch

  prep_w<<<dim3(144), dim3(256), 0, stream>>>(w, wbuf);
  conv_mfma<<<dim3(4096), dim3(512), 0, stream>>>(x, wbuf, b, out);
}

// Round 3
// 263.404 us; speedup vs baseline: 1.2088x; 1.1325x over previous
//
#include <hip/hip_runtime.h>

typedef unsigned short u16;
typedef unsigned int u32;
typedef _Float16 half8 __attribute__((ext_vector_type(8)));
typedef __fp16 fp16x2 __attribute__((ext_vector_type(2)));
typedef float f32x16 __attribute__((ext_vector_type(16)));

union HU { uint4 u; half8 h; };
union PK { fp16x2 h; u32 u; };

__device__ __forceinline__ u16 f2h(float f) {
  union { _Float16 h; u16 u; } c;
  c.h = (_Float16)f;
  return c.u;
}

// Pack weights (O=64, I=64, 3, 3) fp32 -> fp16 in exact A-fragment order:
// wbuf[((t*2 + mt)*64 + lane)*8 + j] = w[m][c][rs]
//   m = mt*32 + (lane&31), k = t*16 + (lane>>5)*8 + j, rs = k>>6, c = k&63
// K ordering: k = rs*64 + c  (rs-major, c-minor); rs = kh*3+kw
// So ktile t = rs*4 + cq where cq = (c>>4) is the channel-quarter.
__global__ void prep_w(const float* __restrict__ w, u16* __restrict__ wbuf) {
  int idx = blockIdx.x * 256 + threadIdx.x;  // 36864 total
  int j    = idx & 7;
  int lane = (idx >> 3) & 63;
  int mt   = (idx >> 9) & 1;
  int t    = idx >> 10;
  int m  = mt * 32 + (lane & 31);
  int k  = t * 16 + (lane >> 5) * 8 + j;
  int rs = k >> 6;
  int c  = k & 63;
  wbuf[idx] = f2h(w[(m * 64 + c) * 9 + rs]);
}

// Implicit-GEMM conv: M = O = 64 (2 mtiles), N = pixels, K = 576.
// v3 schedule: K processed in FOUR 16-channel quarters (cq = 0..3), and the
// weight quarter is staged into LDS alongside the x-tile, so the K-loop is
// pure {ds_read A, ds_read B, MFMA} — no global loads on the critical path.
// (Rounds 0/2 showed ~11% MfmaUtil regardless of occupancy: each MFMA's
// A-fragment was a fresh 16 B global load from L2, ~200 cy exposed latency.)
// Per-phase LDS: x 6 slabs x 130 x 8 ch = 12,480 B  +  w 18 frags x 1 KB =
// 18,432 B  ->  ~31 KB total -> LDS allows 5 blocks/CU; wave cap gives 4
// blocks/CU (32 waves/CU, 100% occupancy) as long as VGPR <= 64.
// Block: one (batch, output row) x 128 px x all 64 o. 512 thr = 8 waves.
// Wave = (mt = wave>>2, nq = wave&3): one 32x32 output tile, acc = f32x16.
// Halo-padded pixel axis (slots 0/129 pre-zeroed once) -> no boundary logic.
// All LDS traffic is lane-contiguous 16 B (b128) -> conflict-free.
// XCD swizzle: 4096 blocks % 8 == 0 -> wg = (bid&7)*512 + bid>>3 gives each
// XCD a contiguous (nb, h) range; adjacent blocks share 2/3 input rows in L2.
__global__ __launch_bounds__(512, 7) void conv_mfma(
    const float* __restrict__ x, const u16* __restrict__ wbuf,
    const float* __restrict__ bias, float* __restrict__ out) {
  __shared__ u16 xlds[6 * 130 * 8];   // 12,480 B: [slab 6 = row3 x cblk2][px-slot 130][ch 8]
  __shared__ u16 wlds[18 * 512];      // 18,432 B: [frag 18 = rs9 x mt2][512]

  int tid = threadIdx.x;
  int lane = tid & 63;
  int wave = tid >> 6;  // 0..7
  int bid = blockIdx.x;
  int wg = ((bid & 7) << 9) | (bid >> 3);  // bijective XCD-contiguous remap
  int nb = wg >> 7;    // batch [0,32)
  int h  = wg & 127;   // output row [0,128)

  int l31 = lane & 31;
  int half = lane >> 5;
  int mt = wave >> 2;  // this wave's mtile
  int nq = wave & 3;   // this wave's 32-pixel ntile

  // zero the halo slots (slot 0 and 129 of each slab) once; staging only
  // ever writes slots 1..128, so these stay zero across all 4 phases.
  if (tid < 6) {
    *(uint4*)&xlds[((tid * 130) + 0) * 8]   = make_uint4(0u, 0u, 0u, 0u);
    *(uint4*)&xlds[((tid * 130) + 129) * 8] = make_uint4(0u, 0u, 0u, 0u);
  }

  f32x16 acc = {};

#pragma unroll
  for (int cq = 0; cq < 4; ++cq) {
    if (cq) __syncthreads();  // previous phase's K-loop must drain before overwrite

    // ---- stage x (channels cq*16 .. +15, rows h-1..h+1) -> LDS ----
    // 12 tasks = (row 3, cblk 2, w-half 2); waves 0..3 do 2, waves 4..7 do 1.
#pragma unroll
    for (int s = 0; s < 2; ++s) {
      int id = s * 8 + wave;  // 0..15, valid < 12
      if (id < 12) {
        int row = id >> 2;        // 0..2
        int cblk = (id >> 1) & 1; // 0..1
        int w2 = id & 1;
        int hin = h - 1 + row;
        int c0 = cq * 16 + cblk * 8;
        bool inb = (hin >= 0 && hin < 128);
        const float* base = x + (((size_t)(nb * 64 + c0) * 128 + hin) * 128);
        int w = w2 * 64 + lane;
        uint4 v = make_uint4(0u, 0u, 0u, 0u);
        if (inb) {
          float f[8];
#pragma unroll
          for (int j = 0; j < 8; ++j) f[j] = base[(size_t)j * 16384 + w];
          PK p0, p1, p2, p3;
          p0.h = __builtin_amdgcn_cvt_pkrtz(f[0], f[1]);
          p1.h = __builtin_amdgcn_cvt_pkrtz(f[2], f[3]);
          p2.h = __builtin_amdgcn_cvt_pkrtz(f[4], f[5]);
          p3.h = __builtin_amdgcn_cvt_pkrtz(f[6], f[7]);
          v = make_uint4(p0.u, p1.u, p2.u, p3.u);
        }
        *(uint4*)&xlds[(((row * 2 + cblk) * 130) + 1 + w) * 8] = v;
      }
    }

    // ---- stage this quarter's weights -> LDS (18 KB linear copy) ----
    // 1152 16B-chunks; local frag f = rs*2+mt holds wbuf frag (rs*4+cq)*2+mt.
#pragma unroll
    for (int i = 0; i < 3; ++i) {
      int idx = i * 512 + tid;  // 16B-chunk index
      if (idx < 1152) {
        int f = idx >> 6;   // local fragment 0..17
        int j = idx & 63;   // chunk within fragment
        int rs = f >> 1;
        int fmt = f & 1;
        int gf = (rs * 4 + cq) * 2 + fmt;
        ((uint4*)wlds)[idx] = ((const uint4*)wbuf)[gf * 64 + j];
      }
    }
    __syncthreads();

    // ---- K-loop: 9 ktiles, pure LDS + MFMA ----
#pragma unroll
    for (int r = 0; r < 3; ++r) {
#pragma unroll
      for (int s = 0; s < 3; ++s) {
        int rs = r * 3 + s;
        int ps = nq * 32 + l31 + s;  // halo-indexed pixel slot, no clamp
        HU a, b;
        a.u = *(const uint4*)&wlds[(rs * 2 + mt) * 512 + lane * 8];
        b.u = *(const uint4*)&xlds[((r * 2 + half) * 130 + ps) * 8];
        acc = __builtin_amdgcn_mfma_f32_32x32x16_f16(a.h, b.h, acc, 0, 0, 0);
      }
    }
  }

  // ---- epilogue: C/D layout col = lane&31 (pixel), row = (reg&3)+8*(reg>>2)+4*half (o) ----
  int p = nq * 32 + l31;
  size_t outbase = (size_t)nb * 64 * 16384 + (size_t)h * 128 + p;
#pragma unroll
  for (int reg = 0; reg < 16; ++reg) {
    int o = mt * 32 + (reg & 3) + 8 * (reg >> 2) + 4 * half;
    out[outbase + (size_t)o * 16384] = acc[reg] + bias[o];
  }
}

extern "C" void kernel_launch(void* const* d_in, const int* in_sizes, int n_in,
                              void* d_out, int out_size, void* d_ws, size_t ws_size,
                              hipStream_t stream) {
  const float* x = (const float*)d_in[0];
  const float* w = (const float*)d_in[1];
  const float* b = (const float*)d_in[2];
  float* out = (float*)d_out;
  u16* wbuf = (u16*)d_ws;  // 36864 fp16 = 73728 B of scratch

  prep_w<<<dim3(144), dim3(256), 0, stream>>>(w, wbuf);
  conv_mfma<<<dim3(4096), dim3(512), 0, stream>>>(x, wbuf, b, out);
}